// Round 1
// 1310.574 us; speedup vs baseline: 1.0818x; 1.0818x over previous
//
#include <hip/hip_runtime.h>
#include <stdint.h>

constexpr int BATCH = 16;
constexpr int LQ = 2048;
constexpr int LK = 2048;
constexpr int DQ = 1024;
constexpr int DK = 1024;
constexpr int DV = 1024;
constexpr float SCALE = 0.03125f;  // 1/sqrt(1024)

typedef __bf16 bf16x8 __attribute__((ext_vector_type(8)));
typedef float f32x4 __attribute__((ext_vector_type(4)));

__device__ __forceinline__ uint16_t f2bf(float x) {
  union { float f; uint32_t u; } v; v.f = x;
  uint32_t r = v.u + 0x7FFFu + ((v.u >> 16) & 1u);  // RNE
  return (uint16_t)(r >> 16);
}

// ---- async global->LDS, 16B per lane (global_load_lds_dwordx4) ----
__device__ __forceinline__ void gload_lds16(const void* gptr, void* lptr) {
  __builtin_amdgcn_global_load_lds((const __attribute__((address_space(1))) void*)gptr,
                                   (__attribute__((address_space(3))) void*)lptr, 16, 0, 0);
}

// ---- stage a 128x32 bf16 tile (k-contiguous global) -> linear LDS [128][32]
//      via global_load_lds. LDS dest is wave-uniform base + lane*16B, so the
//      layout is linear in chunk order c = i*256 + t: row=c>>2, col8=(c&3)*8.
__device__ __forceinline__ void stage_g2l(const uint16_t* __restrict__ g, int ld,
                                          uint16_t* __restrict__ lds, int t) {
  const int wave = t >> 6;
#pragma unroll
  for (int i = 0; i < 2; ++i) {
    const int c = i * 256 + t;
    gload_lds16(g + (size_t)(c >> 2) * ld + ((c & 3) << 3),
                lds + (size_t)(i * 256 + wave * 64) * 8);
  }
}

// ======================= new pure-bf16 m97-structure GEMM =======================
// C[b][m][n] = EPI( sum_k A[b][m][k] * B[b][n][k] ), 128x128 tile, BK=32.
// EPI: 0 = bf16 tanh store (KT), 1 = fp32 store * SCALE (S), 2 = fp32 store (out)
template <int EPI>
__global__ __launch_bounds__(256) void gemm_bf16(const uint16_t* __restrict__ A, long sA, int lda,
                                                 const uint16_t* __restrict__ B, long sB, int ldb,
                                                 void* __restrict__ Cv, long sC, int ldc, int K) {
  __shared__ __align__(16) uint16_t As[128 * 32];
  __shared__ __align__(16) uint16_t Bs[128 * 32];
  const int b = blockIdx.z;
  const int m0 = blockIdx.y * 128;
  const int n0 = blockIdx.x * 128;
  const uint16_t* Ap = A + (size_t)b * sA + (size_t)m0 * lda;
  const uint16_t* Bp = B + (size_t)b * sB + (size_t)n0 * ldb;
  const int t = threadIdx.x;
  const int lane = t & 63;
  const int wave = t >> 6;
  const int wm = (wave >> 1) * 64;
  const int wn = (wave & 1) * 64;
  const int fr = lane & 15;
  const int fk = (lane >> 4) * 8;
  f32x4 acc[4][4];
#pragma unroll
  for (int i = 0; i < 4; ++i)
#pragma unroll
    for (int j = 0; j < 4; ++j) acc[i][j] = f32x4{0.f, 0.f, 0.f, 0.f};

  for (int k0 = 0; k0 < K; k0 += 32) {
    stage_g2l(Ap + k0, lda, As, t);
    stage_g2l(Bp + k0, ldb, Bs, t);
    __syncthreads();  // drains vmcnt (LDS-DMA) before reads
    bf16x8 a[4], bb[4];
#pragma unroll
    for (int i = 0; i < 4; ++i) {
      a[i]  = *(const bf16x8*)(As + (wm + i * 16 + fr) * 32 + fk);
      bb[i] = *(const bf16x8*)(Bs + (wn + i * 16 + fr) * 32 + fk);
    }
#pragma unroll
    for (int mi = 0; mi < 4; ++mi)
#pragma unroll
      for (int ni = 0; ni < 4; ++ni)
        acc[mi][ni] = __builtin_amdgcn_mfma_f32_16x16x32_bf16(a[mi], bb[ni], acc[mi][ni], 0, 0, 0);
    __syncthreads();  // all frag reads done before next DMA overwrites
  }

  const int gm = m0 + wm + (lane >> 4) * 4;
  const int gn = n0 + wn + (lane & 15);
  if constexpr (EPI == 0) {
    uint16_t* C = (uint16_t*)Cv + (size_t)b * sC;
#pragma unroll
    for (int mi = 0; mi < 4; ++mi)
#pragma unroll
      for (int ni = 0; ni < 4; ++ni)
#pragma unroll
        for (int r = 0; r < 4; ++r)
          C[(size_t)(gm + mi * 16 + r) * ldc + (gn + ni * 16)] = f2bf(tanhf(acc[mi][ni][r]));
  } else {
    float* C = (float*)Cv + (size_t)b * sC;
    const float s = (EPI == 1) ? SCALE : 1.0f;
#pragma unroll
    for (int mi = 0; mi < 4; ++mi)
#pragma unroll
      for (int ni = 0; ni < 4; ++ni)
#pragma unroll
        for (int r = 0; r < 4; ++r)
          C[(size_t)(gm + mi * 16 + r) * ldc + (gn + ni * 16)] = acc[mi][ni][r] * s;
  }
}

// ======================= prep kernels (BW-bound; conversion cost lives here) ====
// fp32 -> bf16, 8 elements/thread, contiguous
__global__ __launch_bounds__(256) void cvt_bf16_kernel(const float* __restrict__ src,
                                                       uint16_t* __restrict__ dst) {
  const size_t i = ((size_t)blockIdx.x * 256 + threadIdx.x) * 8;
  float4 a = *(const float4*)(src + i);
  float4 b = *(const float4*)(src + i + 4);
  uint16_t tmp[8] = {f2bf(a.x), f2bf(a.y), f2bf(a.z), f2bf(a.w),
                     f2bf(b.x), f2bf(b.y), f2bf(b.z), f2bf(b.w)};
  *(uint4*)(dst + i) = *(const uint4*)tmp;
}

// v [b][k=2048][n=1024] fp32 -> vT [b][n][k] bf16 (64x64 tiles through LDS)
__global__ __launch_bounds__(256) void transpose_v_kernel(const float* __restrict__ v,
                                                          uint16_t* __restrict__ vt) {
  __shared__ float tile[64][65];
  const int b = blockIdx.z;
  const int k0 = blockIdx.y * 64;
  const int n0 = blockIdx.x * 64;
  const float* src = v + (size_t)b * LK * DV + (size_t)k0 * DV + n0;
  const int t = threadIdx.x;
#pragma unroll
  for (int i = 0; i < 4; ++i) {
    const int idx = i * 256 + t;
    const int r = idx >> 4;
    const int c4 = (idx & 15) * 4;
    float4 f = *(const float4*)(src + (size_t)r * DV + c4);
    tile[r][c4] = f.x; tile[r][c4 + 1] = f.y; tile[r][c4 + 2] = f.z; tile[r][c4 + 3] = f.w;
  }
  __syncthreads();
  const int n = t >> 2;
  const int cg = (t & 3) * 16;
  uint16_t tmp[16];
#pragma unroll
  for (int j = 0; j < 16; ++j) tmp[j] = f2bf(tile[cg + j][n]);
  uint16_t* dst = vt + (size_t)b * DV * LK + (size_t)(n0 + n) * LK + k0 + cg;
  *(uint4*)dst = *(const uint4*)tmp;
  *(uint4*)(dst + 8) = *(const uint4*)(tmp + 8);
}

// ======================= softmax (vectorized contiguous; optional bf16 emit) ====
__global__ __launch_bounds__(256) void softmax_kernel(float* __restrict__ att,
                                                      const int* __restrict__ kidx,
                                                      uint16_t* __restrict__ att16) {
  const int row = blockIdx.x;  // 0..B*LQ-1
  const int b = row >> 11;
  float* p = att + (size_t)row * LK;
  const int* idx = kidx + (size_t)b * LK;
  const int t = threadIdx.x;
  const int j0 = t * 8;
  float4 f0 = *(const float4*)(p + j0);
  float4 f1 = *(const float4*)(p + j0 + 4);
  int4 i0 = *(const int4*)(idx + j0);
  int4 i1 = *(const int4*)(idx + j0 + 4);
  float v[8] = {f0.x, f0.y, f0.z, f0.w, f1.x, f1.y, f1.z, f1.w};
  const int msk[8] = {i0.x, i0.y, i0.z, i0.w, i1.x, i1.y, i1.z, i1.w};
#pragma unroll
  for (int i = 0; i < 8; ++i)
    if (msk[i] == 0) v[i] = -__builtin_inff();
  float mx = v[0];
#pragma unroll
  for (int i = 1; i < 8; ++i) mx = fmaxf(mx, v[i]);
#pragma unroll
  for (int o = 32; o > 0; o >>= 1) mx = fmaxf(mx, __shfl_xor(mx, o, 64));
  __shared__ float redm[4];
  __shared__ float reds[4];
  const int wave = t >> 6, lane = t & 63;
  if (lane == 0) redm[wave] = mx;
  __syncthreads();
  mx = fmaxf(fmaxf(redm[0], redm[1]), fmaxf(redm[2], redm[3]));
  float sum = 0.f;
#pragma unroll
  for (int i = 0; i < 8; ++i) {
    v[i] = __expf(v[i] - mx);  // masked: exp(-inf)=0 -> att exactly 0
    sum += v[i];
  }
#pragma unroll
  for (int o = 32; o > 0; o >>= 1) sum += __shfl_xor(sum, o, 64);
  if (lane == 0) reds[wave] = sum;
  __syncthreads();
  sum = reds[0] + reds[1] + reds[2] + reds[3];
  const float inv = 1.0f / sum;
#pragma unroll
  for (int i = 0; i < 8; ++i) v[i] *= inv;
  *(float4*)(p + j0) = make_float4(v[0], v[1], v[2], v[3]);
  *(float4*)(p + j0 + 4) = make_float4(v[4], v[5], v[6], v[7]);
  if (att16) {
    uint16_t tmp[8] = {f2bf(v[0]), f2bf(v[1]), f2bf(v[2]), f2bf(v[3]),
                       f2bf(v[4]), f2bf(v[5]), f2bf(v[6]), f2bf(v[7])};
    *(uint4*)(att16 + (size_t)row * LK + j0) = *(const uint4*)tmp;
  }
}

// ======================= legacy reg-staged core (PV fallbacks only) =============
__device__ __forceinline__ void stage_f32(const float* __restrict__ g, int ld,
                                          uint16_t* __restrict__ lds, int t) {
#pragma unroll
  for (int i = 0; i < 4; ++i) {
    int c = i * 256 + t;
    int row = c >> 3;
    int col = (c & 7) << 2;
    float4 f = *(const float4*)(g + (size_t)row * ld + col);
    ushort4 h;
    h.x = f2bf(f.x); h.y = f2bf(f.y); h.z = f2bf(f.z); h.w = f2bf(f.w);
    *(ushort4*)(lds + row * 32 + col) = h;
  }
}

__device__ __forceinline__ void stage_bf16(const uint16_t* __restrict__ g, int ld,
                                           uint16_t* __restrict__ lds, int t) {
#pragma unroll
  for (int i = 0; i < 2; ++i) {
    int c = i * 256 + t;
    int row = c >> 2;
    int col = (c & 3) << 3;
    uint4 u = *(const uint4*)(g + (size_t)row * ld + col);
    *(uint4*)(lds + row * 32 + col) = u;
  }
}

__device__ __forceinline__ void stage_f32_T(const float* __restrict__ g, int ld,
                                            uint16_t* __restrict__ lds, int t) {
  const int rp = t & 15;
  const int c0 = (t >> 4) * 8;
  const float* r0 = g + (size_t)(2 * rp) * ld + c0;
  const float* r1 = r0 + ld;
  float4 a0 = *(const float4*)(r0);
  float4 a1 = *(const float4*)(r0 + 4);
  float4 b0 = *(const float4*)(r1);
  float4 b1 = *(const float4*)(r1 + 4);
  float lo[8] = {a0.x, a0.y, a0.z, a0.w, a1.x, a1.y, a1.z, a1.w};
  float hi[8] = {b0.x, b0.y, b0.z, b0.w, b1.x, b1.y, b1.z, b1.w};
  uint32_t* w = (uint32_t*)lds;
#pragma unroll
  for (int j = 0; j < 8; ++j) {
    uint32_t val = (uint32_t)f2bf(lo[j]) | ((uint32_t)f2bf(hi[j]) << 16);
    w[(c0 + j) * 16 + rp] = val;
  }
}

template <int AMODE, int BMODE>
__device__ __forceinline__ void gemm_core(const void* __restrict__ Ap, int lda,
                                          const void* __restrict__ Bp, int ldb,
                                          int K, uint16_t* As, uint16_t* Bs,
                                          f32x4 acc[4][4]) {
  const int t = threadIdx.x;
  const int lane = t & 63;
  const int wave = t >> 6;
  const int wm = (wave >> 1) * 64;
  const int wn = (wave & 1) * 64;
  const int fr = lane & 15;
  const int fk = (lane >> 4) * 8;
  for (int k0 = 0; k0 < K; k0 += 32) {
    if (AMODE == 1) stage_f32((const float*)Ap + k0, lda, As, t);
    else            stage_bf16((const uint16_t*)Ap + k0, lda, As, t);
    if (BMODE == 1)      stage_f32((const float*)Bp + k0, ldb, Bs, t);
    else if (BMODE == 0) stage_bf16((const uint16_t*)Bp + k0, ldb, Bs, t);
    else                 stage_f32_T((const float*)Bp + (size_t)k0 * ldb, ldb, Bs, t);
    __syncthreads();
    bf16x8 a[4], b[4];
#pragma unroll
    for (int i = 0; i < 4; ++i) {
      a[i] = *(const bf16x8*)(As + (wm + i * 16 + fr) * 32 + fk);
      b[i] = *(const bf16x8*)(Bs + (wn + i * 16 + fr) * 32 + fk);
    }
#pragma unroll
    for (int mi = 0; mi < 4; ++mi)
#pragma unroll
      for (int ni = 0; ni < 4; ++ni)
        acc[mi][ni] = __builtin_amdgcn_mfma_f32_16x16x32_bf16(a[mi], b[ni], acc[mi][ni], 0, 0, 0);
    __syncthreads();
  }
}

template <int AMODE, int BMODE>
__device__ __forceinline__ void pv_epilogue_run(const void* A, int lda, const void* B, int ldb,
                                                float* __restrict__ out, int K) {
  __shared__ __align__(16) uint16_t As[128 * 32];
  __shared__ __align__(16) uint16_t Bs[128 * 32];
  f32x4 acc[4][4];
#pragma unroll
  for (int i = 0; i < 4; ++i)
#pragma unroll
    for (int j = 0; j < 4; ++j) acc[i][j] = f32x4{0.f, 0.f, 0.f, 0.f};
  gemm_core<AMODE, BMODE>(A, lda, B, ldb, K, As, Bs, acc);
  const int lane = threadIdx.x & 63;
  const int wave = threadIdx.x >> 6;
  const int m0 = blockIdx.y * 128;
  const int n0 = blockIdx.x * 128;
  const int gm = m0 + (wave >> 1) * 64 + (lane >> 4) * 4;
  const int gn = n0 + (wave & 1) * 64 + (lane & 15);
#pragma unroll
  for (int mi = 0; mi < 4; ++mi)
#pragma unroll
    for (int ni = 0; ni < 4; ++ni)
#pragma unroll
      for (int r = 0; r < 4; ++r)
        out[(size_t)(gm + mi * 16 + r) * DV + (gn + ni * 16)] = acc[mi][ni][r];
}

// PV fallback tiers (d_ws too small for the full bf16 path)
__global__ __launch_bounds__(256) void gemm_pv_kernel(const float* __restrict__ att,
                                                      const float* __restrict__ v,
                                                      float* __restrict__ out) {
  const int b = blockIdx.z;
  pv_epilogue_run<1, 2>(att + (size_t)b * LQ * LK + (size_t)blockIdx.y * 128 * LK, LK,
                        v + (size_t)b * LK * DV + blockIdx.x * 128, DV,
                        out + (size_t)b * LQ * DV, LK);
}

__global__ __launch_bounds__(256) void gemm_pv_a16(const uint16_t* __restrict__ att16,
                                                   const float* __restrict__ v,
                                                   float* __restrict__ out) {
  const int b = blockIdx.z;
  pv_epilogue_run<0, 2>(att16 + (size_t)b * LQ * LK + (size_t)blockIdx.y * 128 * LK, LK,
                        v + (size_t)b * LK * DV + blockIdx.x * 128, DV,
                        out + (size_t)b * LQ * DV, LK);
}

__global__ __launch_bounds__(256) void gemm_pv_bt(const float* __restrict__ att,
                                                  const uint16_t* __restrict__ vt,
                                                  float* __restrict__ out) {
  const int b = blockIdx.z;
  pv_epilogue_run<1, 0>(att + (size_t)b * LQ * LK + (size_t)blockIdx.y * 128 * LK, LK,
                        vt + (size_t)b * DV * LK + (size_t)blockIdx.x * 128 * LK, LK,
                        out + (size_t)b * LQ * DV, LK);
}

// ======================= launch =================================================
// d_out region schedule (R1 = out 134MB, R2 = att 268MB):
//   prep:   q16 -> R1[67,134)   K16 -> R2[0,67)   W16 -> R2[67,69)
//   tanh:   reads K16,W16       writes KT  -> R1[0,67)
//   score:  reads q16,KT        writes S   -> R2 (K16/W16 dead)
//   softmax: in-place R2; emits att16 -> d_ws (if it fits)
//   pv:     reads d_ws (att16,vT) + R2, writes out -> R1 (KT/q16 dead)
extern "C" void kernel_launch(void* const* d_in, const int* in_sizes, int n_in,
                              void* d_out, int out_size, void* d_ws, size_t ws_size,
                              hipStream_t stream) {
  const float* q = (const float*)d_in[0];
  const float* k = (const float*)d_in[1];
  const float* v = (const float*)d_in[2];
  const int* kidx = (const int*)d_in[3];
  const float* W = (const float*)d_in[4];

  float* out = (float*)d_out;
  float* att = out + (size_t)BATCH * LQ * DV;

  uint16_t* KT  = (uint16_t*)d_out;                              // R1[0,67MB)
  uint16_t* q16 = (uint16_t*)d_out + (size_t)BATCH * LQ * DQ;    // R1[67,134MB)
  uint16_t* K16 = (uint16_t*)att;                                // R2[0,67MB)
  uint16_t* W16 = (uint16_t*)att + (size_t)BATCH * LK * DK;      // R2[67,69MB)

  const size_t ATT16_B = (size_t)BATCH * LQ * LK * 2;  // 134217728
  const size_t VT_B    = (size_t)BATCH * DV * LK * 2;  // 67108864
  const bool has_a16 = ws_size >= ATT16_B;
  const bool has_vt  = (ws_size >= ATT16_B + VT_B) || (!has_a16 && ws_size >= VT_B);
  uint16_t* att16 = (uint16_t*)d_ws;
  uint16_t* vt = has_a16 ? (uint16_t*)d_ws + ATT16_B / 2 : (uint16_t*)d_ws;

  // prep (BW-bound; all fp32->bf16 conversion amortized here)
  cvt_bf16_kernel<<<16384, 256, 0, stream>>>(k, K16);
  cvt_bf16_kernel<<<16384, 256, 0, stream>>>(q, q16);
  cvt_bf16_kernel<<<512, 256, 0, stream>>>(W, W16);
  if (has_vt) transpose_v_kernel<<<dim3(16, 32, BATCH), 256, 0, stream>>>(v, vt);

  // GEMM1: KT = bf16(tanh(K @ W^T)), M=32768 N=1024 K=1024
  gemm_bf16<0><<<dim3(DQ / 128, (BATCH * LK) / 128, 1), 256, 0, stream>>>(
      K16, 0, DK, W16, 0, DK, (void*)KT, 0, DQ, DK);

  // GEMM2: S = SCALE * q @ KT^T  (per batch), M=2048 N=2048 K=1024
  gemm_bf16<1><<<dim3(LK / 128, LQ / 128, BATCH), 256, 0, stream>>>(
      q16, (long)LQ * DQ, DQ, KT, (long)LK * DQ, DQ, (void*)att, (long)LQ * LK, LK, DQ);

  softmax_kernel<<<BATCH * LQ, 256, 0, stream>>>(att, kidx, has_a16 ? att16 : nullptr);

  // GEMM3: out = att @ v  (per batch), M=2048 N=1024 K=2048
  if (has_a16 && has_vt)
    gemm_bf16<2><<<dim3(DV / 128, LQ / 128, BATCH), 256, 0, stream>>>(
        att16, (long)LQ * LK, LK, vt, (long)DV * LK, LK, (void*)out, (long)LQ * DV, DV, LK);
  else if (has_a16)
    gemm_pv_a16<<<dim3(DV / 128, LQ / 128, BATCH), 256, 0, stream>>>(att16, v, out);
  else if (has_vt)
    gemm_pv_bt<<<dim3(DV / 128, LQ / 128, BATCH), 256, 0, stream>>>(att, vt, out);
  else
    gemm_pv_kernel<<<dim3(DV / 128, LQ / 128, BATCH), 256, 0, stream>>>(att, v, out);
}

// Round 2
// 1282.797 us; speedup vs baseline: 1.1052x; 1.0217x over previous
//
#include <hip/hip_runtime.h>
#include <stdint.h>

constexpr int BATCH = 16;
constexpr int LQ = 2048;
constexpr int LK = 2048;
constexpr int DQ = 1024;
constexpr int DK = 1024;
constexpr int DV = 1024;
constexpr float SCALE = 0.03125f;  // 1/sqrt(1024)

typedef __bf16 bf16x8 __attribute__((ext_vector_type(8)));
typedef float f32x4 __attribute__((ext_vector_type(4)));

__device__ __forceinline__ uint16_t f2bf(float x) {
  union { float f; uint32_t u; } v; v.f = x;
  uint32_t r = v.u + 0x7FFFu + ((v.u >> 16) & 1u);  // RNE
  return (uint16_t)(r >> 16);
}

// ---- async global->LDS, 16B per lane (global_load_lds_dwordx4) ----
__device__ __forceinline__ void gload_lds16(const void* gptr, void* lptr) {
  __builtin_amdgcn_global_load_lds((const __attribute__((address_space(1))) void*)gptr,
                                   (__attribute__((address_space(3))) void*)lptr, 16, 0, 0);
}

// ---- stage a 128x32 bf16 tile (k-contiguous global, compile-time ld) ->
//      linear LDS [128][32] via global_load_lds. LDS dest = wave-uniform base
//      + lane*16B (HW adds the lane offset). 2 loads/thread = 4 vmcnt events/wave.
template <int LD>
__device__ __forceinline__ void stage_g2l(const uint16_t* __restrict__ g,
                                          uint16_t* __restrict__ lds, int t) {
  const int wave = t >> 6;
#pragma unroll
  for (int i = 0; i < 2; ++i) {
    const int c = i * 256 + t;
    gload_lds16(g + (size_t)(c >> 2) * LD + ((c & 3) << 3),
                lds + (size_t)(i * 256 + wave * 64) * 8);
  }
}

// ======================= pipelined bf16 GEMM (3-buffer, depth-2, counted vmcnt) =
// C[b][m][n] = EPI( sum_k A[b][m][k] * B[b][n][k] ), 128x128 tile, BK=32.
// EPI: 0 = bf16 tanh store (KT), 1 = fp32 store * SCALE (S), 2 = fp32 store (out)
// Pipeline invariant (4 gload_lds per tile per thread, strict FIFO vmcnt):
//   in-loop outstanding after staging tile t+2 = 8 (t+1's 4 + t+2's 4);
//   s_waitcnt vmcnt(4) retires exactly tile t+1's loads before the barrier,
//   so every wave's DMA for the tile read next iter is complete at barrier.
template <int EPI, int LDA, int LDB, int K, int LDC>
__global__ __launch_bounds__(256) void gemm_bf16p(const uint16_t* __restrict__ A, long sA,
                                                  const uint16_t* __restrict__ B, long sB,
                                                  void* __restrict__ Cv, long sC) {
  constexpr int NT = K / 32;
  static_assert(NT >= 2, "pipeline needs >=2 K-tiles");
  __shared__ __align__(16) uint16_t As[3][128 * 32];
  __shared__ __align__(16) uint16_t Bs[3][128 * 32];
  const int b = blockIdx.z;
  const int m0 = blockIdx.y * 128;
  const int n0 = blockIdx.x * 128;
  const uint16_t* Ap = A + (size_t)b * sA + (size_t)m0 * LDA;
  const uint16_t* Bp = B + (size_t)b * sB + (size_t)n0 * LDB;
  const int t = threadIdx.x;
  const int lane = t & 63;
  const int wave = t >> 6;
  const int wm = (wave >> 1) * 64;
  const int wn = (wave & 1) * 64;
  const int fr = lane & 15;
  const int fk = (lane >> 4) * 8;
  f32x4 acc[4][4];
#pragma unroll
  for (int i = 0; i < 4; ++i)
#pragma unroll
    for (int j = 0; j < 4; ++j) acc[i][j] = f32x4{0.f, 0.f, 0.f, 0.f};

  // prologue: stage tiles 0 and 1; wait tile 0 (oldest 4), keep tile 1 in flight
  stage_g2l<LDA>(Ap, As[0], t);
  stage_g2l<LDB>(Bp, Bs[0], t);
  stage_g2l<LDA>(Ap + 32, As[1], t);
  stage_g2l<LDB>(Bp + 32, Bs[1], t);
  asm volatile("s_waitcnt vmcnt(4)" ::: "memory");
  __builtin_amdgcn_s_barrier();

  int cur = 0;
  for (int kt = 0; kt < NT; ++kt) {
    if (kt + 2 < NT) {  // issue tile kt+2 into the buffer freed two iters ago
      int nxt = cur + 2; if (nxt >= 3) nxt -= 3;
      stage_g2l<LDA>(Ap + (size_t)(kt + 2) * 32, As[nxt], t);
      stage_g2l<LDB>(Bp + (size_t)(kt + 2) * 32, Bs[nxt], t);
    }
    bf16x8 a[4], bb[4];
#pragma unroll
    for (int i = 0; i < 4; ++i) {
      a[i]  = *(const bf16x8*)(&As[cur][(wm + i * 16 + fr) * 32 + fk]);
      bb[i] = *(const bf16x8*)(&Bs[cur][(wn + i * 16 + fr) * 32 + fk]);
    }
#pragma unroll
    for (int mi = 0; mi < 4; ++mi)
#pragma unroll
      for (int ni = 0; ni < 4; ++ni)
        acc[mi][ni] = __builtin_amdgcn_mfma_f32_16x16x32_bf16(a[mi], bb[ni], acc[mi][ni], 0, 0, 0);
    if (kt + 2 < NT) asm volatile("s_waitcnt vmcnt(4)" ::: "memory");
    else             asm volatile("s_waitcnt vmcnt(0)" ::: "memory");
    __builtin_amdgcn_s_barrier();
    cur += 1; if (cur >= 3) cur -= 3;
  }

  const int gm = m0 + wm + (lane >> 4) * 4;
  const int gn = n0 + wn + (lane & 15);
  if constexpr (EPI == 0) {
    uint16_t* C = (uint16_t*)Cv + (size_t)b * sC;
#pragma unroll
    for (int mi = 0; mi < 4; ++mi)
#pragma unroll
      for (int ni = 0; ni < 4; ++ni)
#pragma unroll
        for (int r = 0; r < 4; ++r)
          C[(size_t)(gm + mi * 16 + r) * LDC + (gn + ni * 16)] = f2bf(tanhf(acc[mi][ni][r]));
  } else {
    float* C = (float*)Cv + (size_t)b * sC;
    const float s = (EPI == 1) ? SCALE : 1.0f;
#pragma unroll
    for (int mi = 0; mi < 4; ++mi)
#pragma unroll
      for (int ni = 0; ni < 4; ++ni)
#pragma unroll
        for (int r = 0; r < 4; ++r)
          C[(size_t)(gm + mi * 16 + r) * LDC + (gn + ni * 16)] = acc[mi][ni][r] * s;
  }
}

// ======================= prep kernels (BW-bound; conversion cost lives here) ====
__global__ __launch_bounds__(256) void cvt_bf16_kernel(const float* __restrict__ src,
                                                       uint16_t* __restrict__ dst) {
  const size_t i = ((size_t)blockIdx.x * 256 + threadIdx.x) * 8;
  float4 a = *(const float4*)(src + i);
  float4 b = *(const float4*)(src + i + 4);
  uint16_t tmp[8] = {f2bf(a.x), f2bf(a.y), f2bf(a.z), f2bf(a.w),
                     f2bf(b.x), f2bf(b.y), f2bf(b.z), f2bf(b.w)};
  *(uint4*)(dst + i) = *(const uint4*)tmp;
}

// v [b][k=2048][n=1024] fp32 -> vT [b][n][k] bf16 (64x64 tiles through LDS)
__global__ __launch_bounds__(256) void transpose_v_kernel(const float* __restrict__ v,
                                                          uint16_t* __restrict__ vt) {
  __shared__ float tile[64][65];
  const int b = blockIdx.z;
  const int k0 = blockIdx.y * 64;
  const int n0 = blockIdx.x * 64;
  const float* src = v + (size_t)b * LK * DV + (size_t)k0 * DV + n0;
  const int t = threadIdx.x;
#pragma unroll
  for (int i = 0; i < 4; ++i) {
    const int idx = i * 256 + t;
    const int r = idx >> 4;
    const int c4 = (idx & 15) * 4;
    float4 f = *(const float4*)(src + (size_t)r * DV + c4);
    tile[r][c4] = f.x; tile[r][c4 + 1] = f.y; tile[r][c4 + 2] = f.z; tile[r][c4 + 3] = f.w;
  }
  __syncthreads();
  const int n = t >> 2;
  const int cg = (t & 3) * 16;
  uint16_t tmp[16];
#pragma unroll
  for (int j = 0; j < 16; ++j) tmp[j] = f2bf(tile[cg + j][n]);
  uint16_t* dst = vt + (size_t)b * DV * LK + (size_t)(n0 + n) * LK + k0 + cg;
  *(uint4*)dst = *(const uint4*)tmp;
  *(uint4*)(dst + 8) = *(const uint4*)(tmp + 8);
}

// ======================= softmax (vectorized contiguous; bf16 emit) =============
__global__ __launch_bounds__(256) void softmax_kernel(float* __restrict__ att,
                                                      const int* __restrict__ kidx,
                                                      uint16_t* __restrict__ att16) {
  const int row = blockIdx.x;  // 0..B*LQ-1
  const int b = row >> 11;
  float* p = att + (size_t)row * LK;
  const int* idx = kidx + (size_t)b * LK;
  const int t = threadIdx.x;
  const int j0 = t * 8;
  float4 f0 = *(const float4*)(p + j0);
  float4 f1 = *(const float4*)(p + j0 + 4);
  int4 i0 = *(const int4*)(idx + j0);
  int4 i1 = *(const int4*)(idx + j0 + 4);
  float v[8] = {f0.x, f0.y, f0.z, f0.w, f1.x, f1.y, f1.z, f1.w};
  const int msk[8] = {i0.x, i0.y, i0.z, i0.w, i1.x, i1.y, i1.z, i1.w};
#pragma unroll
  for (int i = 0; i < 8; ++i)
    if (msk[i] == 0) v[i] = -__builtin_inff();
  float mx = v[0];
#pragma unroll
  for (int i = 1; i < 8; ++i) mx = fmaxf(mx, v[i]);
#pragma unroll
  for (int o = 32; o > 0; o >>= 1) mx = fmaxf(mx, __shfl_xor(mx, o, 64));
  __shared__ float redm[4];
  __shared__ float reds[4];
  const int wave = t >> 6, lane = t & 63;
  if (lane == 0) redm[wave] = mx;
  __syncthreads();
  mx = fmaxf(fmaxf(redm[0], redm[1]), fmaxf(redm[2], redm[3]));
  float sum = 0.f;
#pragma unroll
  for (int i = 0; i < 8; ++i) {
    v[i] = __expf(v[i] - mx);  // masked: exp(-inf)=0 -> att exactly 0
    sum += v[i];
  }
#pragma unroll
  for (int o = 32; o > 0; o >>= 1) sum += __shfl_xor(sum, o, 64);
  if (lane == 0) reds[wave] = sum;
  __syncthreads();
  sum = reds[0] + reds[1] + reds[2] + reds[3];
  const float inv = 1.0f / sum;
#pragma unroll
  for (int i = 0; i < 8; ++i) v[i] *= inv;
  *(float4*)(p + j0) = make_float4(v[0], v[1], v[2], v[3]);
  *(float4*)(p + j0 + 4) = make_float4(v[4], v[5], v[6], v[7]);
  if (att16) {
    uint16_t tmp[8] = {f2bf(v[0]), f2bf(v[1]), f2bf(v[2]), f2bf(v[3]),
                       f2bf(v[4]), f2bf(v[5]), f2bf(v[6]), f2bf(v[7])};
    *(uint4*)(att16 + (size_t)row * LK + j0) = *(const uint4*)tmp;
  }
}

// ======================= legacy reg-staged core (PV fallbacks only) =============
__device__ __forceinline__ void stage_f32(const float* __restrict__ g, int ld,
                                          uint16_t* __restrict__ lds, int t) {
#pragma unroll
  for (int i = 0; i < 4; ++i) {
    int c = i * 256 + t;
    int row = c >> 3;
    int col = (c & 7) << 2;
    float4 f = *(const float4*)(g + (size_t)row * ld + col);
    ushort4 h;
    h.x = f2bf(f.x); h.y = f2bf(f.y); h.z = f2bf(f.z); h.w = f2bf(f.w);
    *(ushort4*)(lds + row * 32 + col) = h;
  }
}

__device__ __forceinline__ void stage_bf16(const uint16_t* __restrict__ g, int ld,
                                           uint16_t* __restrict__ lds, int t) {
#pragma unroll
  for (int i = 0; i < 2; ++i) {
    int c = i * 256 + t;
    int row = c >> 2;
    int col = (c & 3) << 3;
    uint4 u = *(const uint4*)(g + (size_t)row * ld + col);
    *(uint4*)(lds + row * 32 + col) = u;
  }
}

__device__ __forceinline__ void stage_f32_T(const float* __restrict__ g, int ld,
                                            uint16_t* __restrict__ lds, int t) {
  const int rp = t & 15;
  const int c0 = (t >> 4) * 8;
  const float* r0 = g + (size_t)(2 * rp) * ld + c0;
  const float* r1 = r0 + ld;
  float4 a0 = *(const float4*)(r0);
  float4 a1 = *(const float4*)(r0 + 4);
  float4 b0 = *(const float4*)(r1);
  float4 b1 = *(const float4*)(r1 + 4);
  float lo[8] = {a0.x, a0.y, a0.z, a0.w, a1.x, a1.y, a1.z, a1.w};
  float hi[8] = {b0.x, b0.y, b0.z, b0.w, b1.x, b1.y, b1.z, b1.w};
  uint32_t* w = (uint32_t*)lds;
#pragma unroll
  for (int j = 0; j < 8; ++j) {
    uint32_t val = (uint32_t)f2bf(lo[j]) | ((uint32_t)f2bf(hi[j]) << 16);
    w[(c0 + j) * 16 + rp] = val;
  }
}

template <int AMODE, int BMODE>
__device__ __forceinline__ void gemm_core(const void* __restrict__ Ap, int lda,
                                          const void* __restrict__ Bp, int ldb,
                                          int K, uint16_t* As, uint16_t* Bs,
                                          f32x4 acc[4][4]) {
  const int t = threadIdx.x;
  const int lane = t & 63;
  const int wave = t >> 6;
  const int wm = (wave >> 1) * 64;
  const int wn = (wave & 1) * 64;
  const int fr = lane & 15;
  const int fk = (lane >> 4) * 8;
  for (int k0 = 0; k0 < K; k0 += 32) {
    if (AMODE == 1) stage_f32((const float*)Ap + k0, lda, As, t);
    else            stage_bf16((const uint16_t*)Ap + k0, lda, As, t);
    if (BMODE == 1)      stage_f32((const float*)Bp + k0, ldb, Bs, t);
    else if (BMODE == 0) stage_bf16((const uint16_t*)Bp + k0, ldb, Bs, t);
    else                 stage_f32_T((const float*)Bp + (size_t)k0 * ldb, ldb, Bs, t);
    __syncthreads();
    bf16x8 a[4], b[4];
#pragma unroll
    for (int i = 0; i < 4; ++i) {
      a[i] = *(const bf16x8*)(As + (wm + i * 16 + fr) * 32 + fk);
      b[i] = *(const bf16x8*)(Bs + (wn + i * 16 + fr) * 32 + fk);
    }
#pragma unroll
    for (int mi = 0; mi < 4; ++mi)
#pragma unroll
      for (int ni = 0; ni < 4; ++ni)
        acc[mi][ni] = __builtin_amdgcn_mfma_f32_16x16x32_bf16(a[mi], b[ni], acc[mi][ni], 0, 0, 0);
    __syncthreads();
  }
}

template <int AMODE, int BMODE>
__device__ __forceinline__ void pv_epilogue_run(const void* A, int lda, const void* B, int ldb,
                                                float* __restrict__ out, int K) {
  __shared__ __align__(16) uint16_t As[128 * 32];
  __shared__ __align__(16) uint16_t Bs[128 * 32];
  f32x4 acc[4][4];
#pragma unroll
  for (int i = 0; i < 4; ++i)
#pragma unroll
    for (int j = 0; j < 4; ++j) acc[i][j] = f32x4{0.f, 0.f, 0.f, 0.f};
  gemm_core<AMODE, BMODE>(A, lda, B, ldb, K, As, Bs, acc);
  const int lane = threadIdx.x & 63;
  const int wave = threadIdx.x >> 6;
  const int m0 = blockIdx.y * 128;
  const int n0 = blockIdx.x * 128;
  const int gm = m0 + (wave >> 1) * 64 + (lane >> 4) * 4;
  const int gn = n0 + (wave & 1) * 64 + (lane & 15);
#pragma unroll
  for (int mi = 0; mi < 4; ++mi)
#pragma unroll
    for (int ni = 0; ni < 4; ++ni)
#pragma unroll
      for (int r = 0; r < 4; ++r)
        out[(size_t)(gm + mi * 16 + r) * DV + (gn + ni * 16)] = acc[mi][ni][r];
}

// PV fallback tiers (d_ws too small for the full bf16 path)
__global__ __launch_bounds__(256) void gemm_pv_kernel(const float* __restrict__ att,
                                                      const float* __restrict__ v,
                                                      float* __restrict__ out) {
  const int b = blockIdx.z;
  pv_epilogue_run<1, 2>(att + (size_t)b * LQ * LK + (size_t)blockIdx.y * 128 * LK, LK,
                        v + (size_t)b * LK * DV + blockIdx.x * 128, DV,
                        out + (size_t)b * LQ * DV, LK);
}

__global__ __launch_bounds__(256) void gemm_pv_a16(const uint16_t* __restrict__ att16,
                                                   const float* __restrict__ v,
                                                   float* __restrict__ out) {
  const int b = blockIdx.z;
  pv_epilogue_run<0, 2>(att16 + (size_t)b * LQ * LK + (size_t)blockIdx.y * 128 * LK, LK,
                        v + (size_t)b * LK * DV + blockIdx.x * 128, DV,
                        out + (size_t)b * LQ * DV, LK);
}

__global__ __launch_bounds__(256) void gemm_pv_bt(const float* __restrict__ att,
                                                  const uint16_t* __restrict__ vt,
                                                  float* __restrict__ out) {
  const int b = blockIdx.z;
  pv_epilogue_run<1, 0>(att + (size_t)b * LQ * LK + (size_t)blockIdx.y * 128 * LK, LK,
                        vt + (size_t)b * DV * LK + (size_t)blockIdx.x * 128 * LK, LK,
                        out + (size_t)b * LQ * DV, LK);
}

// ======================= launch =================================================
// d_out region schedule (R1 = out 134MB, R2 = att 268MB):
//   prep:   q16 -> R1[67,134)   K16 -> R2[0,67)   W16 -> R2[67,69)
//   tanh:   reads K16,W16       writes KT  -> R1[0,67)
//   score:  reads q16,KT        writes S   -> R2 (K16/W16 dead)
//   softmax: in-place R2; emits att16 -> d_ws
//   pv:     reads d_ws (att16,vT), writes out -> R1 (KT/q16 dead)
extern "C" void kernel_launch(void* const* d_in, const int* in_sizes, int n_in,
                              void* d_out, int out_size, void* d_ws, size_t ws_size,
                              hipStream_t stream) {
  const float* q = (const float*)d_in[0];
  const float* k = (const float*)d_in[1];
  const float* v = (const float*)d_in[2];
  const int* kidx = (const int*)d_in[3];
  const float* W = (const float*)d_in[4];

  float* out = (float*)d_out;
  float* att = out + (size_t)BATCH * LQ * DV;

  uint16_t* KT  = (uint16_t*)d_out;                              // R1[0,67MB)
  uint16_t* q16 = (uint16_t*)d_out + (size_t)BATCH * LQ * DQ;    // R1[67,134MB)
  uint16_t* K16 = (uint16_t*)att;                                // R2[0,67MB)
  uint16_t* W16 = (uint16_t*)att + (size_t)BATCH * LK * DK;      // R2[67,69MB)

  const size_t ATT16_B = (size_t)BATCH * LQ * LK * 2;  // 134217728
  const size_t VT_B    = (size_t)BATCH * DV * LK * 2;  // 67108864
  const bool has_a16 = ws_size >= ATT16_B;
  const bool has_vt  = (ws_size >= ATT16_B + VT_B) || (!has_a16 && ws_size >= VT_B);
  uint16_t* att16 = (uint16_t*)d_ws;
  uint16_t* vt = has_a16 ? (uint16_t*)d_ws + ATT16_B / 2 : (uint16_t*)d_ws;

  // prep (BW-bound; all fp32->bf16 conversion amortized here)
  cvt_bf16_kernel<<<16384, 256, 0, stream>>>(k, K16);
  cvt_bf16_kernel<<<16384, 256, 0, stream>>>(q, q16);
  cvt_bf16_kernel<<<512, 256, 0, stream>>>(W, W16);
  if (has_vt) transpose_v_kernel<<<dim3(16, 32, BATCH), 256, 0, stream>>>(v, vt);

  // GEMM1: KT = bf16(tanh(K @ W^T)), M=32768 N=1024 K=1024
  gemm_bf16p<0, DK, DK, DK, DQ><<<dim3(DQ / 128, (BATCH * LK) / 128, 1), 256, 0, stream>>>(
      K16, 0, W16, 0, (void*)KT, 0);

  // GEMM2: S = SCALE * q @ KT^T  (per batch), M=2048 N=2048 K=1024
  gemm_bf16p<1, DQ, DQ, DQ, LK><<<dim3(LK / 128, LQ / 128, BATCH), 256, 0, stream>>>(
      q16, (long)LQ * DQ, KT, (long)LK * DQ, (void*)att, (long)LQ * LK);

  softmax_kernel<<<BATCH * LQ, 256, 0, stream>>>(att, kidx, has_a16 ? att16 : nullptr);

  // GEMM3: out = att @ v  (per batch), M=2048 N=1024 K=2048
  if (has_a16 && has_vt)
    gemm_bf16p<2, LK, LK, LK, DV><<<dim3(DV / 128, LQ / 128, BATCH), 256, 0, stream>>>(
        att16, (long)LQ * LK, vt, (long)DV * LK, (void*)out, (long)LQ * DV);
  else if (has_a16)
    gemm_pv_a16<<<dim3(DV / 128, LQ / 128, BATCH), 256, 0, stream>>>(att16, v, out);
  else if (has_vt)
    gemm_pv_bt<<<dim3(DV / 128, LQ / 128, BATCH), 256, 0, stream>>>(att, vt, out);
  else
    gemm_pv_kernel<<<dim3(DV / 128, LQ / 128, BATCH), 256, 0, stream>>>(att, v, out);
}

// Round 3
// 1262.120 us; speedup vs baseline: 1.1233x; 1.0164x over previous
//
#include <hip/hip_runtime.h>
#include <stdint.h>

constexpr int BATCH = 16;
constexpr int LQ = 2048;
constexpr int LK = 2048;
constexpr int DQ = 1024;
constexpr int DK = 1024;
constexpr int DV = 1024;
constexpr float SCALE = 0.03125f;  // 1/sqrt(1024)

typedef __bf16 bf16x8 __attribute__((ext_vector_type(8)));
typedef float f32x4 __attribute__((ext_vector_type(4)));

__device__ __forceinline__ uint16_t f2bf(float x) {
  union { float f; uint32_t u; } v; v.f = x;
  uint32_t r = v.u + 0x7FFFu + ((v.u >> 16) & 1u);  // RNE
  return (uint16_t)(r >> 16);
}

// ---- async global->LDS, 16B per lane (global_load_lds_dwordx4) ----
__device__ __forceinline__ void gload_lds16(const void* gptr, void* lptr) {
  __builtin_amdgcn_global_load_lds((const __attribute__((address_space(1))) void*)gptr,
                                   (__attribute__((address_space(3))) void*)lptr, 16, 0, 0);
}

// ================= 256x256 8-phase GEMM (m198-style, linear LDS) ================
// Geometry: BM=BN=256, BK=64, 512 threads = 8 waves (2M x 4N), per-wave C 128x64.
// LDS: As[2][256][64] + Bs[2][256][64] bf16 = 128 KiB (double-buffered K-tiles).
// Half-tile = 128 rows x 64 k of one operand = 2 gload_lds16 per thread.
//
// stage_half: rows half*128..+127 of a [256][64] tile, linear LDS layout.
// chunk c = i*512 + t: row = c>>3, col8 = (c&7)*8; LDS dest = base + c*16B
// (wave-uniform base + lane*16B, HW adds lane offset).
template <int LD>
__device__ __forceinline__ void stage_half(const uint16_t* __restrict__ g,
                                           uint16_t* __restrict__ lds_tile,
                                           int half, int t) {
  const int wave = t >> 6;
#pragma unroll
  for (int i = 0; i < 2; ++i) {
    const int c = i * 512 + t;
    gload_lds16(g + (size_t)(half * 128 + (c >> 3)) * LD + ((c & 7) << 3),
                lds_tile + ((half * 1024 + i * 512 + wave * 64) << 3));
  }
}

// One K-tile (BK=64) = 4 phases. Quadrants: ph0=(mh0,nh0) ph1=(mh0,nh1)
// ph2=(mh1,nh1) ph3=(mh1,nh0). Slot lifetimes (all proven with barriers):
//   B[BUF] fully lgkm-retired after ph1 -> ph2/ph3 stage tile T+2's B halves.
//   A[BUF^1] (tile T-1's A) freed after prev tile's ph2 -> ph0/ph1 stage T+1's A.
// vmcnt(4) at tile end keeps only tile T+2's 2 B half-tiles (4 loads) in flight;
// retires everything needed for tile T+1 before its ph0 reads.
template <int LDA, int LDB, int NT, int BUF>
__device__ __forceinline__ void tile_step(
    const uint16_t* __restrict__ Ap, const uint16_t* __restrict__ Bp,
    uint16_t (&As)[2][256 * 64], uint16_t (&Bs)[2][256 * 64],
    int kt, int t, int wm, int wn, int fr, int fk, f32x4 (&acc)[8][4]) {
  const uint16_t* al = As[BUF];
  const uint16_t* bl = Bs[BUF];
  bf16x8 aA[4][2], b0[2][2], b1[2][2];
  // ---- phase 0: read A(mh0) 8x + B(nh0) 4x; stage (T+1).A half0; MFMA q(0,0)
#pragma unroll
  for (int mf = 0; mf < 4; ++mf)
#pragma unroll
    for (int s = 0; s < 2; ++s)
      aA[mf][s] = *(const bf16x8*)(al + (wm * 128 + mf * 16 + fr) * 64 + s * 32 + fk);
#pragma unroll
  for (int nf = 0; nf < 2; ++nf)
#pragma unroll
    for (int s = 0; s < 2; ++s)
      b0[nf][s] = *(const bf16x8*)(bl + (wn * 64 + nf * 16 + fr) * 64 + s * 32 + fk);
  if (kt + 1 < NT) stage_half<LDA>(Ap + (size_t)(kt + 1) * 64, As[BUF ^ 1], 0, t);
  __builtin_amdgcn_s_barrier();
  asm volatile("s_waitcnt lgkmcnt(0)" ::: "memory");
  __builtin_amdgcn_s_setprio(1);
#pragma unroll
  for (int s = 0; s < 2; ++s)
#pragma unroll
    for (int mf = 0; mf < 4; ++mf)
#pragma unroll
      for (int nf = 0; nf < 2; ++nf)
        acc[mf][nf] =
            __builtin_amdgcn_mfma_f32_16x16x32_bf16(aA[mf][s], b0[nf][s], acc[mf][nf], 0, 0, 0);
  __builtin_amdgcn_s_setprio(0);
  __builtin_amdgcn_s_barrier();
  // ---- phase 1: read B(nh1) 4x; stage (T+1).A half1; MFMA q(0,1)
#pragma unroll
  for (int nf = 0; nf < 2; ++nf)
#pragma unroll
    for (int s = 0; s < 2; ++s)
      b1[nf][s] = *(const bf16x8*)(bl + (wn * 64 + 32 + nf * 16 + fr) * 64 + s * 32 + fk);
  if (kt + 1 < NT) stage_half<LDA>(Ap + (size_t)(kt + 1) * 64, As[BUF ^ 1], 1, t);
  __builtin_amdgcn_s_barrier();
  asm volatile("s_waitcnt lgkmcnt(0)" ::: "memory");
  __builtin_amdgcn_s_setprio(1);
#pragma unroll
  for (int s = 0; s < 2; ++s)
#pragma unroll
    for (int mf = 0; mf < 4; ++mf)
#pragma unroll
      for (int nf = 0; nf < 2; ++nf)
        acc[mf][2 + nf] =
            __builtin_amdgcn_mfma_f32_16x16x32_bf16(aA[mf][s], b1[nf][s], acc[mf][2 + nf], 0, 0, 0);
  __builtin_amdgcn_s_setprio(0);
  __builtin_amdgcn_s_barrier();
  // ---- phase 2: read A(mh1) 8x (reuse aA regs); stage (T+2).B half0; MFMA q(1,1)
#pragma unroll
  for (int mf = 0; mf < 4; ++mf)
#pragma unroll
    for (int s = 0; s < 2; ++s)
      aA[mf][s] = *(const bf16x8*)(al + (wm * 128 + 64 + mf * 16 + fr) * 64 + s * 32 + fk);
  if (kt + 2 < NT) stage_half<LDB>(Bp + (size_t)(kt + 2) * 64, Bs[BUF], 0, t);
  __builtin_amdgcn_s_barrier();
  asm volatile("s_waitcnt lgkmcnt(0)" ::: "memory");
  __builtin_amdgcn_s_setprio(1);
#pragma unroll
  for (int s = 0; s < 2; ++s)
#pragma unroll
    for (int mf = 0; mf < 4; ++mf)
#pragma unroll
      for (int nf = 0; nf < 2; ++nf)
        acc[4 + mf][2 + nf] = __builtin_amdgcn_mfma_f32_16x16x32_bf16(aA[mf][s], b1[nf][s],
                                                                      acc[4 + mf][2 + nf], 0, 0, 0);
  __builtin_amdgcn_s_setprio(0);
  __builtin_amdgcn_s_barrier();
  // ---- phase 3: stage (T+2).B half1; MFMA q(1,0) (regs only); counted vmcnt
  if (kt + 2 < NT) stage_half<LDB>(Bp + (size_t)(kt + 2) * 64, Bs[BUF], 1, t);
  __builtin_amdgcn_s_setprio(1);
#pragma unroll
  for (int s = 0; s < 2; ++s)
#pragma unroll
    for (int mf = 0; mf < 4; ++mf)
#pragma unroll
      for (int nf = 0; nf < 2; ++nf)
        acc[4 + mf][nf] =
            __builtin_amdgcn_mfma_f32_16x16x32_bf16(aA[mf][s], b0[nf][s], acc[4 + mf][nf], 0, 0, 0);
  __builtin_amdgcn_s_setprio(0);
  if (kt + 2 < NT) asm volatile("s_waitcnt vmcnt(4)" ::: "memory");
  else             asm volatile("s_waitcnt vmcnt(0)" ::: "memory");
  __builtin_amdgcn_s_barrier();
}

// C[b][m][n] = EPI( sum_k A[b][m][k]*B[b][n][k] ).
// EPI: 0 = bf16 tanh store (KT), 1 = fp32 store * SCALE (S), 2 = fp32 store (out)
template <int EPI, int LDA, int LDB, int K, int LDC>
__global__ __launch_bounds__(512) void gemm256(const uint16_t* __restrict__ A, long sA,
                                               const uint16_t* __restrict__ B, long sB,
                                               void* __restrict__ Cv, long sC) {
  constexpr int NT = K / 64;
  static_assert(NT >= 4 && (NT & 1) == 0, "need even NT >= 4");
  __shared__ __align__(16) uint16_t As[2][256 * 64];
  __shared__ __align__(16) uint16_t Bs[2][256 * 64];
  const int b = blockIdx.z;
  const int m0 = blockIdx.y * 256;
  const int n0 = blockIdx.x * 256;
  const uint16_t* Ap = A + (size_t)b * sA + (size_t)m0 * LDA;
  const uint16_t* Bp = B + (size_t)b * sB + (size_t)n0 * LDB;
  const int t = threadIdx.x;
  const int lane = t & 63;
  const int wave = t >> 6;
  const int wm = wave >> 2;   // 0..1 (M)
  const int wn = wave & 3;    // 0..3 (N)
  const int fr = lane & 15;
  const int fk = (lane >> 4) * 8;
  f32x4 acc[8][4];
#pragma unroll
  for (int i = 0; i < 8; ++i)
#pragma unroll
    for (int j = 0; j < 4; ++j) acc[i][j] = f32x4{0.f, 0.f, 0.f, 0.f};

  // prologue (FIFO: T0.B0 T0.B1 T0.A0 T0.A1 T1.B0 T1.B1 = 12 loads/thread):
  stage_half<LDB>(Bp, Bs[0], 0, t);
  stage_half<LDB>(Bp, Bs[0], 1, t);
  stage_half<LDA>(Ap, As[0], 0, t);
  stage_half<LDA>(Ap, As[0], 1, t);
  stage_half<LDB>(Bp + 64, Bs[1], 0, t);
  stage_half<LDB>(Bp + 64, Bs[1], 1, t);
  asm volatile("s_waitcnt vmcnt(4)" ::: "memory");  // T0 landed; T1.B in flight
  __builtin_amdgcn_s_barrier();

  for (int kt = 0; kt < NT; kt += 2) {
    tile_step<LDA, LDB, NT, 0>(Ap, Bp, As, Bs, kt, t, wm, wn, fr, fk, acc);
    tile_step<LDA, LDB, NT, 1>(Ap, Bp, As, Bs, kt + 1, t, wm, wn, fr, fk, acc);
  }

  const int gm = m0 + wm * 128 + (lane >> 4) * 4;
  const int gn = n0 + wn * 64 + (lane & 15);
  if constexpr (EPI == 0) {
    uint16_t* C = (uint16_t*)Cv + (size_t)b * sC;
#pragma unroll
    for (int mi = 0; mi < 8; ++mi)
#pragma unroll
      for (int ni = 0; ni < 4; ++ni)
#pragma unroll
        for (int r = 0; r < 4; ++r)
          C[(size_t)(gm + mi * 16 + r) * LDC + (gn + ni * 16)] = f2bf(tanhf(acc[mi][ni][r]));
  } else {
    float* C = (float*)Cv + (size_t)b * sC;
    const float s = (EPI == 1) ? SCALE : 1.0f;
#pragma unroll
    for (int mi = 0; mi < 8; ++mi)
#pragma unroll
      for (int ni = 0; ni < 4; ++ni)
#pragma unroll
        for (int r = 0; r < 4; ++r)
          C[(size_t)(gm + mi * 16 + r) * LDC + (gn + ni * 16)] = acc[mi][ni][r] * s;
  }
}

// ======================= prep kernels (BW-bound; conversion cost lives here) ====
__global__ __launch_bounds__(256) void cvt_bf16_kernel(const float* __restrict__ src,
                                                       uint16_t* __restrict__ dst) {
  const size_t i = ((size_t)blockIdx.x * 256 + threadIdx.x) * 8;
  float4 a = *(const float4*)(src + i);
  float4 b = *(const float4*)(src + i + 4);
  uint16_t tmp[8] = {f2bf(a.x), f2bf(a.y), f2bf(a.z), f2bf(a.w),
                     f2bf(b.x), f2bf(b.y), f2bf(b.z), f2bf(b.w)};
  *(uint4*)(dst + i) = *(const uint4*)tmp;
}

// v [b][k=2048][n=1024] fp32 -> vT [b][n][k] bf16 (64x64 tiles through LDS)
__global__ __launch_bounds__(256) void transpose_v_kernel(const float* __restrict__ v,
                                                          uint16_t* __restrict__ vt) {
  __shared__ float tile[64][65];
  const int b = blockIdx.z;
  const int k0 = blockIdx.y * 64;
  const int n0 = blockIdx.x * 64;
  const float* src = v + (size_t)b * LK * DV + (size_t)k0 * DV + n0;
  const int t = threadIdx.x;
#pragma unroll
  for (int i = 0; i < 4; ++i) {
    const int idx = i * 256 + t;
    const int r = idx >> 4;
    const int c4 = (idx & 15) * 4;
    float4 f = *(const float4*)(src + (size_t)r * DV + c4);
    tile[r][c4] = f.x; tile[r][c4 + 1] = f.y; tile[r][c4 + 2] = f.z; tile[r][c4 + 3] = f.w;
  }
  __syncthreads();
  const int n = t >> 2;
  const int cg = (t & 3) * 16;
  uint16_t tmp[16];
#pragma unroll
  for (int j = 0; j < 16; ++j) tmp[j] = f2bf(tile[cg + j][n]);
  uint16_t* dst = vt + (size_t)b * DV * LK + (size_t)(n0 + n) * LK + k0 + cg;
  *(uint4*)dst = *(const uint4*)tmp;
  *(uint4*)(dst + 8) = *(const uint4*)(tmp + 8);
}

// ======================= softmax (vectorized contiguous; bf16 emit) =============
__global__ __launch_bounds__(256) void softmax_kernel(float* __restrict__ att,
                                                      const int* __restrict__ kidx,
                                                      uint16_t* __restrict__ att16) {
  const int row = blockIdx.x;  // 0..B*LQ-1
  const int b = row >> 11;
  float* p = att + (size_t)row * LK;
  const int* idx = kidx + (size_t)b * LK;
  const int t = threadIdx.x;
  const int j0 = t * 8;
  float4 f0 = *(const float4*)(p + j0);
  float4 f1 = *(const float4*)(p + j0 + 4);
  int4 i0 = *(const int4*)(idx + j0);
  int4 i1 = *(const int4*)(idx + j0 + 4);
  float v[8] = {f0.x, f0.y, f0.z, f0.w, f1.x, f1.y, f1.z, f1.w};
  const int msk[8] = {i0.x, i0.y, i0.z, i0.w, i1.x, i1.y, i1.z, i1.w};
#pragma unroll
  for (int i = 0; i < 8; ++i)
    if (msk[i] == 0) v[i] = -__builtin_inff();
  float mx = v[0];
#pragma unroll
  for (int i = 1; i < 8; ++i) mx = fmaxf(mx, v[i]);
#pragma unroll
  for (int o = 32; o > 0; o >>= 1) mx = fmaxf(mx, __shfl_xor(mx, o, 64));
  __shared__ float redm[4];
  __shared__ float reds[4];
  const int wave = t >> 6, lane = t & 63;
  if (lane == 0) redm[wave] = mx;
  __syncthreads();
  mx = fmaxf(fmaxf(redm[0], redm[1]), fmaxf(redm[2], redm[3]));
  float sum = 0.f;
#pragma unroll
  for (int i = 0; i < 8; ++i) {
    v[i] = __expf(v[i] - mx);  // masked: exp(-inf)=0 -> att exactly 0
    sum += v[i];
  }
#pragma unroll
  for (int o = 32; o > 0; o >>= 1) sum += __shfl_xor(sum, o, 64);
  if (lane == 0) reds[wave] = sum;
  __syncthreads();
  sum = reds[0] + reds[1] + reds[2] + reds[3];
  const float inv = 1.0f / sum;
#pragma unroll
  for (int i = 0; i < 8; ++i) v[i] *= inv;
  *(float4*)(p + j0) = make_float4(v[0], v[1], v[2], v[3]);
  *(float4*)(p + j0 + 4) = make_float4(v[4], v[5], v[6], v[7]);
  if (att16) {
    uint16_t tmp[8] = {f2bf(v[0]), f2bf(v[1]), f2bf(v[2]), f2bf(v[3]),
                       f2bf(v[4]), f2bf(v[5]), f2bf(v[6]), f2bf(v[7])};
    *(uint4*)(att16 + (size_t)row * LK + j0) = *(const uint4*)tmp;
  }
}

// ======================= legacy reg-staged core (PV fallbacks only) =============
__device__ __forceinline__ void stage_f32(const float* __restrict__ g, int ld,
                                          uint16_t* __restrict__ lds, int t) {
#pragma unroll
  for (int i = 0; i < 4; ++i) {
    int c = i * 256 + t;
    int row = c >> 3;
    int col = (c & 7) << 2;
    float4 f = *(const float4*)(g + (size_t)row * ld + col);
    ushort4 h;
    h.x = f2bf(f.x); h.y = f2bf(f.y); h.z = f2bf(f.z); h.w = f2bf(f.w);
    *(ushort4*)(lds + row * 32 + col) = h;
  }
}

__device__ __forceinline__ void stage_bf16(const uint16_t* __restrict__ g, int ld,
                                           uint16_t* __restrict__ lds, int t) {
#pragma unroll
  for (int i = 0; i < 2; ++i) {
    int c = i * 256 + t;
    int row = c >> 2;
    int col = (c & 3) << 3;
    uint4 u = *(const uint4*)(g + (size_t)row * ld + col);
    *(uint4*)(lds + row * 32 + col) = u;
  }
}

__device__ __forceinline__ void stage_f32_T(const float* __restrict__ g, int ld,
                                            uint16_t* __restrict__ lds, int t) {
  const int rp = t & 15;
  const int c0 = (t >> 4) * 8;
  const float* r0 = g + (size_t)(2 * rp) * ld + c0;
  const float* r1 = r0 + ld;
  float4 a0 = *(const float4*)(r0);
  float4 a1 = *(const float4*)(r0 + 4);
  float4 b0 = *(const float4*)(r1);
  float4 b1 = *(const float4*)(r1 + 4);
  float lo[8] = {a0.x, a0.y, a0.z, a0.w, a1.x, a1.y, a1.z, a1.w};
  float hi[8] = {b0.x, b0.y, b0.z, b0.w, b1.x, b1.y, b1.z, b1.w};
  uint32_t* w = (uint32_t*)lds;
#pragma unroll
  for (int j = 0; j < 8; ++j) {
    uint32_t val = (uint32_t)f2bf(lo[j]) | ((uint32_t)f2bf(hi[j]) << 16);
    w[(c0 + j) * 16 + rp] = val;
  }
}

template <int AMODE, int BMODE>
__device__ __forceinline__ void gemm_core(const void* __restrict__ Ap, int lda,
                                          const void* __restrict__ Bp, int ldb,
                                          int K, uint16_t* As, uint16_t* Bs,
                                          f32x4 acc[4][4]) {
  const int t = threadIdx.x;
  const int lane = t & 63;
  const int wave = t >> 6;
  const int wm = (wave >> 1) * 64;
  const int wn = (wave & 1) * 64;
  const int fr = lane & 15;
  const int fk = (lane >> 4) * 8;
  for (int k0 = 0; k0 < K; k0 += 32) {
    if (AMODE == 1) stage_f32((const float*)Ap + k0, lda, As, t);
    else            stage_bf16((const uint16_t*)Ap + k0, lda, As, t);
    if (BMODE == 1)      stage_f32((const float*)Bp + k0, ldb, Bs, t);
    else if (BMODE == 0) stage_bf16((const uint16_t*)Bp + k0, ldb, Bs, t);
    else                 stage_f32_T((const float*)Bp + (size_t)k0 * ldb, ldb, Bs, t);
    __syncthreads();
    bf16x8 a[4], b[4];
#pragma unroll
    for (int i = 0; i < 4; ++i) {
      a[i] = *(const bf16x8*)(As + (wm + i * 16 + fr) * 32 + fk);
      b[i] = *(const bf16x8*)(Bs + (wn + i * 16 + fr) * 32 + fk);
    }
#pragma unroll
    for (int mi = 0; mi < 4; ++mi)
#pragma unroll
      for (int ni = 0; ni < 4; ++ni)
        acc[mi][ni] = __builtin_amdgcn_mfma_f32_16x16x32_bf16(a[mi], b[ni], acc[mi][ni], 0, 0, 0);
    __syncthreads();
  }
}

template <int AMODE, int BMODE>
__device__ __forceinline__ void pv_epilogue_run(const void* A, int lda, const void* B, int ldb,
                                                float* __restrict__ out, int K) {
  __shared__ __align__(16) uint16_t As[128 * 32];
  __shared__ __align__(16) uint16_t Bs[128 * 32];
  f32x4 acc[4][4];
#pragma unroll
  for (int i = 0; i < 4; ++i)
#pragma unroll
    for (int j = 0; j < 4; ++j) acc[i][j] = f32x4{0.f, 0.f, 0.f, 0.f};
  gemm_core<AMODE, BMODE>(A, lda, B, ldb, K, As, Bs, acc);
  const int lane = threadIdx.x & 63;
  const int wave = threadIdx.x >> 6;
  const int m0 = blockIdx.y * 128;
  const int n0 = blockIdx.x * 128;
  const int gm = m0 + (wave >> 1) * 64 + (lane >> 4) * 4;
  const int gn = n0 + (wave & 1) * 64 + (lane & 15);
#pragma unroll
  for (int mi = 0; mi < 4; ++mi)
#pragma unroll
    for (int ni = 0; ni < 4; ++ni)
#pragma unroll
      for (int r = 0; r < 4; ++r)
        out[(size_t)(gm + mi * 16 + r) * DV + (gn + ni * 16)] = acc[mi][ni][r];
}

// PV fallback tiers (d_ws too small for the full bf16 path)
__global__ __launch_bounds__(256) void gemm_pv_kernel(const float* __restrict__ att,
                                                      const float* __restrict__ v,
                                                      float* __restrict__ out) {
  const int b = blockIdx.z;
  pv_epilogue_run<1, 2>(att + (size_t)b * LQ * LK + (size_t)blockIdx.y * 128 * LK, LK,
                        v + (size_t)b * LK * DV + blockIdx.x * 128, DV,
                        out + (size_t)b * LQ * DV, LK);
}

__global__ __launch_bounds__(256) void gemm_pv_a16(const uint16_t* __restrict__ att16,
                                                   const float* __restrict__ v,
                                                   float* __restrict__ out) {
  const int b = blockIdx.z;
  pv_epilogue_run<0, 2>(att16 + (size_t)b * LQ * LK + (size_t)blockIdx.y * 128 * LK, LK,
                        v + (size_t)b * LK * DV + blockIdx.x * 128, DV,
                        out + (size_t)b * LQ * DV, LK);
}

__global__ __launch_bounds__(256) void gemm_pv_bt(const float* __restrict__ att,
                                                  const uint16_t* __restrict__ vt,
                                                  float* __restrict__ out) {
  const int b = blockIdx.z;
  pv_epilogue_run<1, 0>(att + (size_t)b * LQ * LK + (size_t)blockIdx.y * 128 * LK, LK,
                        vt + (size_t)b * DV * LK + (size_t)blockIdx.x * 128 * LK, LK,
                        out + (size_t)b * LQ * DV, LK);
}

// ======================= launch =================================================
// d_out region schedule (R1 = out 134MB, R2 = att 268MB):
//   prep:   q16 -> R1[67,134)   K16 -> R2[0,67)   W16 -> R2[67,69)
//   tanh:   reads K16,W16       writes KT  -> R1[0,67)
//   score:  reads q16,KT        writes S   -> R2 (K16/W16 dead)
//   softmax: in-place R2; emits att16 -> d_ws
//   pv:     reads d_ws (att16,vT), writes out -> R1 (KT/q16 dead)
extern "C" void kernel_launch(void* const* d_in, const int* in_sizes, int n_in,
                              void* d_out, int out_size, void* d_ws, size_t ws_size,
                              hipStream_t stream) {
  const float* q = (const float*)d_in[0];
  const float* k = (const float*)d_in[1];
  const float* v = (const float*)d_in[2];
  const int* kidx = (const int*)d_in[3];
  const float* W = (const float*)d_in[4];

  float* out = (float*)d_out;
  float* att = out + (size_t)BATCH * LQ * DV;

  uint16_t* KT  = (uint16_t*)d_out;                              // R1[0,67MB)
  uint16_t* q16 = (uint16_t*)d_out + (size_t)BATCH * LQ * DQ;    // R1[67,134MB)
  uint16_t* K16 = (uint16_t*)att;                                // R2[0,67MB)
  uint16_t* W16 = (uint16_t*)att + (size_t)BATCH * LK * DK;      // R2[67,69MB)

  const size_t ATT16_B = (size_t)BATCH * LQ * LK * 2;  // 134217728
  const size_t VT_B    = (size_t)BATCH * DV * LK * 2;  // 67108864
  const bool has_a16 = ws_size >= ATT16_B;
  const bool has_vt  = (ws_size >= ATT16_B + VT_B) || (!has_a16 && ws_size >= VT_B);
  uint16_t* att16 = (uint16_t*)d_ws;
  uint16_t* vt = has_a16 ? (uint16_t*)d_ws + ATT16_B / 2 : (uint16_t*)d_ws;

  // prep (BW-bound; all fp32->bf16 conversion amortized here)
  cvt_bf16_kernel<<<16384, 256, 0, stream>>>(k, K16);
  cvt_bf16_kernel<<<16384, 256, 0, stream>>>(q, q16);
  cvt_bf16_kernel<<<512, 256, 0, stream>>>(W, W16);
  if (has_vt) transpose_v_kernel<<<dim3(16, 32, BATCH), 256, 0, stream>>>(v, vt);

  // GEMM1: KT = bf16(tanh(K @ W^T)), M=32768 N=1024 K=1024
  gemm256<0, DK, DK, DK, DQ><<<dim3(DQ / 256, (BATCH * LK) / 256, 1), 512, 0, stream>>>(
      K16, 0, W16, 0, (void*)KT, 0);

  // GEMM2: S = SCALE * q @ KT^T  (per batch), M=2048 N=2048 K=1024
  gemm256<1, DQ, DQ, DQ, LK><<<dim3(LK / 256, LQ / 256, BATCH), 512, 0, stream>>>(
      q16, (long)LQ * DQ, KT, (long)LK * DQ, (void*)att, (long)LQ * LK);

  softmax_kernel<<<BATCH * LQ, 256, 0, stream>>>(att, kidx, has_a16 ? att16 : nullptr);

  // GEMM3: out = att @ v  (per batch), M=2048 N=1024 K=2048
  if (has_a16 && has_vt)
    gemm256<2, LK, LK, LK, DV><<<dim3(DV / 256, LQ / 256, BATCH), 512, 0, stream>>>(
        att16, (long)LQ * LK, vt, (long)DV * LK, (void*)out, (long)LQ * DV);
  else if (has_a16)
    gemm_pv_a16<<<dim3(DV / 128, LQ / 128, BATCH), 256, 0, stream>>>(att16, v, out);
  else if (has_vt)
    gemm_pv_bt<<<dim3(DV / 128, LQ / 128, BATCH), 256, 0, stream>>>(att, vt, out);
  else
    gemm_pv_kernel<<<dim3(DV / 128, LQ / 128, BATCH), 256, 0, stream>>>(att, v, out);
}